// Round 11
// baseline (208.479 us; speedup 1.0000x reference)
//
#include <hip/hip_runtime.h>

#define DF 128
#define NBKT_MAX 256   // coarse buckets = ceil(N/256); N=50000 -> 196
#define CAP 8192       // fixed per-bucket edge capacity (avg 4082 at E=800K; 2x slack)
// packing assumes src < 2^24 and N <= 65536 (srcs stored as ushort). N=50000 here.

typedef unsigned int uint;
typedef unsigned short ushort;
typedef __attribute__((ext_vector_type(8))) short short8;   // 8 bf16 (4 VGPR) MFMA A/B frag
typedef __attribute__((ext_vector_type(4))) float f32x4;    // MFMA C/D frag

union frag_u { uint4 u4; short8 s8; };

__device__ __forceinline__ uint f2u(float f) { return __float_as_uint(f); }
__device__ __forceinline__ ushort rne_bf16(float v) {
    uint u = __float_as_uint(v);
    u = u + 0x7FFFu + ((u >> 16) & 1u);
    return (ushort)(u >> 16);
}
__device__ __forceinline__ float bflo(uint u) { return __uint_as_float(u << 16); }
__device__ __forceinline__ float bfhi(uint u) { return __uint_as_float(u & 0xFFFF0000u); }

// ============ scatter + wprep fused ============
// blocks [0,SB): scatter edges (int2-vectorized reads) into fixed-cap bucket regions.
// blocks [SB,SB+16): W1/W2 -> hi/lo bf16 B-frag layout.
__global__ __launch_bounds__(256) void scatter_wprep(const int* __restrict__ src,
                                                     const int* __restrict__ dst,
                                                     int* __restrict__ ccur,
                                                     uint* __restrict__ ebuf,
                                                     int E, int NB, int SB,
                                                     const float* __restrict__ W1,
                                                     const float* __restrict__ W2,
                                                     uint4* __restrict__ Whi,
                                                     uint4* __restrict__ Wlo) {
    __shared__ int cnt[NBKT_MAX];
    __shared__ int base[NBKT_MAX];
    int t = threadIdx.x;
    if ((int)blockIdx.x < SB) {
        int e0 = blockIdx.x * 8192, e1 = min(E, e0 + 8192);
        int p0 = e0 >> 1, p1 = e1 >> 1;            // e0 always even
        const int2* dst2 = (const int2*)dst;
        const int2* src2 = (const int2*)src;
        for (int i = t; i < NB; i += 256) cnt[i] = 0;
        __syncthreads();
        for (int p = p0 + t; p < p1; p += 256) {
            int2 d = dst2[p];
            atomicAdd(&cnt[d.x >> 8], 1);
            atomicAdd(&cnt[d.y >> 8], 1);
        }
        if (t == 0 && (e1 & 1)) atomicAdd(&cnt[dst[e1 - 1] >> 8], 1);
        __syncthreads();
        for (int i = t; i < NB; i += 256) base[i] = cnt[i] ? atomicAdd(&ccur[i], cnt[i]) : 0;
        __syncthreads();
        for (int p = p0 + t; p < p1; p += 256) {
            int2 d = dst2[p];
            int2 s = src2[p];
            int b0 = d.x >> 8;
            int q0 = atomicAdd(&base[b0], 1);
            if (q0 < CAP) ebuf[(size_t)b0 * CAP + q0] = ((uint)(d.x & 255) << 24) | (uint)s.x;
            int b1 = d.y >> 8;
            int q1 = atomicAdd(&base[b1], 1);
            if (q1 < CAP) ebuf[(size_t)b1 * CAP + q1] = ((uint)(d.y & 255) << 24) | (uint)s.y;
        }
        if (t == 0 && (e1 & 1)) {
            int d = dst[e1 - 1], b = d >> 8;
            int q = atomicAdd(&base[b], 1);
            if (q < CAP) ebuf[(size_t)b * CAP + q] = ((uint)(d & 255) << 24) | (uint)src[e1 - 1];
        }
    } else {
        int tt4 = ((int)blockIdx.x - SB) * 256 + t;   // 0..4095
        int wsel = tt4 >> 11;
        int tt = tt4 & 2047;
        const float* W = wsel ? W2 : W1;
        int lane = tt & 63;
        int n  = ((tt >> 6) & 7) * 16 + (lane & 15);
        int k0 = (tt >> 9) * 32 + (lane >> 4) * 8;
        uint hi[4], lo[4];
#pragma unroll
        for (int p = 0; p < 4; ++p) {
            float f0 = W[(size_t)(k0 + 2 * p) * DF + n];
            float f1 = W[(size_t)(k0 + 2 * p + 1) * DF + n];
            uint u0 = f2u(f0), u1 = f2u(f1);
            hi[p] = (u1 & 0xFFFF0000u) | (u0 >> 16);                 // truncation split
            float l0 = f0 - __uint_as_float(u0 & 0xFFFF0000u);       // exact residual
            float l1 = f1 - __uint_as_float(u1 & 0xFFFF0000u);
            lo[p] = (f2u(l1) & 0xFFFF0000u) | (f2u(l0) >> 16);
        }
        Whi[wsel * 2048 + tt] = make_uint4(hi[0], hi[1], hi[2], hi[3]);
        Wlo[wsel * 2048 + tt] = make_uint4(lo[0], lo[1], lo[2], lo[3]);
    }
}

// ============ bucket sort: fine-sort each bucket by dst ============
// LDS *int* atomics only. Never per-element fp32 atomics: fp32 atomic op throughput
// is ~150 G/s chip-wide regardless of memory space (R1 vs R7/R8).
__global__ __launch_bounds__(256) void bucket_sort(const uint* __restrict__ ebuf,
                                                   const int* __restrict__ ccur,
                                                   int* __restrict__ rstart,
                                                   int* __restrict__ rend,
                                                   float* __restrict__ dinv,
                                                   ushort* __restrict__ srcs,
                                                   int N) {
    __shared__ int cnt[256];
    __shared__ int sp[256];
    int t = threadIdx.x, b = blockIdx.x;
    int count = min(ccur[b], CAP);
    const uint* eb = ebuf + (size_t)b * CAP;
    cnt[t] = 0;
    __syncthreads();
    for (int j = t; j < count; j += 256) atomicAdd(&cnt[eb[j] >> 24], 1);
    __syncthreads();
    int v = cnt[t];
    sp[t] = v;
    __syncthreads();
    for (int off = 1; off < 256; off <<= 1) {
        int x = (t >= off) ? sp[t - off] : 0;
        __syncthreads();
        sp[t] += x;
        __syncthreads();
    }
    int ex = sp[t] - v;                 // exclusive local offset
    int node = b * 256 + t;
    if (node < N) {
        rstart[node] = b * CAP + ex;
        rend[node]   = b * CAP + ex + v;
        dinv[node] = rsqrtf((float)v + 1.0f);   // +1 = self-loop
    }
    sp[t] = ex;                          // becomes local cursor
    __syncthreads();
    for (int j = t; j < count; j += 256) {
        uint e = eb[j];
        int pos = atomicAdd(&sp[e >> 24], 1);
        srcs[(size_t)b * CAP + pos] = (ushort)(e & 0xFFFFFFu);
    }
}

// ============ MFMA GEMM (fp32 A, 3-product split): Hh = bf16((A@W)*dinv), half-major ============
// Hh layout: [h][node][64 dims] bf16, h = dim/64 (128 B per node-half)
__global__ __launch_bounds__(256) void gemm_f32A(const float* __restrict__ A,
                                                 const uint4* __restrict__ Bhi,
                                                 const uint4* __restrict__ Blo,
                                                 const float* __restrict__ dinv,
                                                 ushort* __restrict__ Hh, int M) {
    const int lane = threadIdx.x & 63;
    const int w = threadIdx.x >> 6;
    const int l15 = lane & 15, quad = lane >> 4;
    const int rowbase = blockIdx.x * 128 + w * 32;

    f32x4 acc[2][8];
#pragma unroll
    for (int rt = 0; rt < 2; ++rt)
#pragma unroll
        for (int ct = 0; ct < 8; ++ct) acc[rt][ct] = (f32x4){0.f, 0.f, 0.f, 0.f};

    for (int q = 0; q < 4; ++q) {
        frag_u ah[2], al[2];
#pragma unroll
        for (int rt = 0; rt < 2; ++rt) {
            int m = rowbase + rt * 16 + l15;
            if (m >= M) m = M - 1;                  // clamp; stores guarded below
            const float* ap = A + (size_t)m * DF + q * 32 + quad * 8;
            float4 v0 = *(const float4*)ap;
            float4 v1 = *(const float4*)(ap + 4);
            float f[8] = {v0.x, v0.y, v0.z, v0.w, v1.x, v1.y, v1.z, v1.w};
            uint hi[4], lo[4];
#pragma unroll
            for (int p = 0; p < 4; ++p) {
                uint u0 = f2u(f[2 * p]), u1 = f2u(f[2 * p + 1]);
                hi[p] = (u1 & 0xFFFF0000u) | (u0 >> 16);
                float l0 = f[2 * p]     - __uint_as_float(u0 & 0xFFFF0000u);
                float l1 = f[2 * p + 1] - __uint_as_float(u1 & 0xFFFF0000u);
                lo[p] = (f2u(l1) & 0xFFFF0000u) | (f2u(l0) >> 16);
            }
            ah[rt].u4 = make_uint4(hi[0], hi[1], hi[2], hi[3]);
            al[rt].u4 = make_uint4(lo[0], lo[1], lo[2], lo[3]);
        }
#pragma unroll
        for (int ct = 0; ct < 8; ++ct) {
            frag_u bh, bl;
            bh.u4 = Bhi[(q * 8 + ct) * 64 + lane];
            bl.u4 = Blo[(q * 8 + ct) * 64 + lane];
#pragma unroll
            for (int rt = 0; rt < 2; ++rt) {
                acc[rt][ct] = __builtin_amdgcn_mfma_f32_16x16x32_bf16(al[rt].s8, bh.s8, acc[rt][ct], 0, 0, 0);
                acc[rt][ct] = __builtin_amdgcn_mfma_f32_16x16x32_bf16(ah[rt].s8, bl.s8, acc[rt][ct], 0, 0, 0);
                acc[rt][ct] = __builtin_amdgcn_mfma_f32_16x16x32_bf16(ah[rt].s8, bh.s8, acc[rt][ct], 0, 0, 0);
            }
        }
    }
    // epilogue: col = ct*16+l15 -> h = ct>>2, d = (ct&3)*16+l15; row = rt*16+quad*4+reg
#pragma unroll
    for (int rt = 0; rt < 2; ++rt)
#pragma unroll
        for (int reg = 0; reg < 4; ++reg) {
            int row = rowbase + rt * 16 + quad * 4 + reg;
            if (row < M) {
                float di = dinv[row];
#pragma unroll
                for (int ct = 0; ct < 8; ++ct)
                    Hh[((size_t)(ct >> 2) * M + row) * 64 + (ct & 3) * 16 + l15] =
                        rne_bf16(acc[rt][ct][reg] * di);
            }
        }
}

// ============ MFMA GEMM (bf16 A half-major, no relu): Hh = bf16((A@W)*dinv) ============
__global__ __launch_bounds__(256) void gemm_bf16A(const ushort* __restrict__ A,
                                                  const uint4* __restrict__ Bhi,
                                                  const uint4* __restrict__ Blo,
                                                  const float* __restrict__ dinv,
                                                  ushort* __restrict__ Hh, int M) {
    const int lane = threadIdx.x & 63;
    const int w = threadIdx.x >> 6;
    const int l15 = lane & 15, quad = lane >> 4;
    const int rowbase = blockIdx.x * 128 + w * 32;

    f32x4 acc[2][8];
#pragma unroll
    for (int rt = 0; rt < 2; ++rt)
#pragma unroll
        for (int ct = 0; ct < 8; ++ct) acc[rt][ct] = (f32x4){0.f, 0.f, 0.f, 0.f};

    for (int q = 0; q < 4; ++q) {
        frag_u a[2];
#pragma unroll
        for (int rt = 0; rt < 2; ++rt) {
            int m = rowbase + rt * 16 + l15;
            if (m >= M) m = M - 1;
            // A dims [q*32 + quad*8, +8): half h=q>>1, offset (q&1)*32 + quad*8
            const ushort* ap = A + ((size_t)(q >> 1) * M + m) * 64 + (q & 1) * 32 + quad * 8;
            a[rt].u4 = *(const uint4*)ap;
        }
#pragma unroll
        for (int ct = 0; ct < 8; ++ct) {
            frag_u bh, bl;
            bh.u4 = Bhi[(q * 8 + ct) * 64 + lane];
            bl.u4 = Blo[(q * 8 + ct) * 64 + lane];
#pragma unroll
            for (int rt = 0; rt < 2; ++rt) {
                acc[rt][ct] = __builtin_amdgcn_mfma_f32_16x16x32_bf16(a[rt].s8, bl.s8, acc[rt][ct], 0, 0, 0);
                acc[rt][ct] = __builtin_amdgcn_mfma_f32_16x16x32_bf16(a[rt].s8, bh.s8, acc[rt][ct], 0, 0, 0);
            }
        }
    }
#pragma unroll
    for (int rt = 0; rt < 2; ++rt)
#pragma unroll
        for (int reg = 0; reg < 4; ++reg) {
            int row = rowbase + rt * 16 + quad * 4 + reg;
            if (row < M) {
                float di = dinv[row];
#pragma unroll
                for (int ct = 0; ct < 8; ++ct)
                    Hh[((size_t)(ct >> 2) * M + row) * 64 + (ct & 3) * 16 + l15] =
                        rne_bf16(acc[rt][ct][reg] * di);
            }
        }
}

// ============ half gather: 8-lane groups, uint4/lane (128B half-row per group) ============
// Half-major tables: dst lists walked 2x (vs 4x quarter / R10) -> srcs + loop overhead halved.
// srcs: lane l loads srcs[j+l] (one 16B group-load for 8 edges), rows distributed via
// __shfl(sv,r,8) -> 8 rows in flight per group (2x R10 MLP). One VMEM instr = 8 rows = 1KB.
// half = bid&1 -> 4-XCD class per 6.4MB half-table (16MB L2). Zero fp32 atomics.
template<bool L1>
__global__ __launch_bounds__(256) void half_gather(const uint4* __restrict__ H4,
                                                   const float* __restrict__ dinv,
                                                   const int* __restrict__ rstart,
                                                   const int* __restrict__ rend,
                                                   const ushort* __restrict__ srcs,
                                                   const float* __restrict__ bias,
                                                   void* __restrict__ outv, int N) {
    int t = threadIdx.x;
    int bid = blockIdx.x;
    int sub = bid & 7;
    int h = sub & 1;
    int slice = sub >> 1;                                   // 0..3
    int n = (bid >> 3) * 128 + slice * 32 + (t >> 3);       // one dst per 8-lane group
    if (n >= N) return;
    int l = t & 7;                                          // lane's uint4 within 128B row
    const uint4* Hh = H4 + (size_t)h * N * 8;               // half table, 8 uint4/node

    float4 bb0 = ((const float4*)bias)[h * 16 + l * 2];
    float4 bb1 = ((const float4*)bias)[h * 16 + l * 2 + 1];

    uint4 self = Hh[(size_t)n * 8 + l];                     // self-loop H'[n]
    float a0 = bflo(self.x), a1 = bfhi(self.x), a2 = bflo(self.y), a3 = bfhi(self.y);
    float a4 = bflo(self.z), a5 = bfhi(self.z), a6 = bflo(self.w), a7 = bfhi(self.w);

    int j = rstart[n], end = rend[n];
    while (j + 8 <= end) {
        int sv = srcs[j + l];                               // 8 edges, one 16B group-load
        uint4 v[8];
#pragma unroll
        for (int r = 0; r < 8; ++r) {
            int s = __shfl(sv, r, 8);
            v[r] = Hh[(size_t)s * 8 + l];                   // 8 rows in flight
        }
#pragma unroll
        for (int r = 0; r < 8; ++r) {
            a0 += bflo(v[r].x); a1 += bfhi(v[r].x);
            a2 += bflo(v[r].y); a3 += bfhi(v[r].y);
            a4 += bflo(v[r].z); a5 += bfhi(v[r].z);
            a6 += bflo(v[r].w); a7 += bfhi(v[r].w);
        }
        j += 8;
    }
    for (; j < end; ++j) {
        uint4 v = Hh[(size_t)srcs[j] * 8 + l];
        a0 += bflo(v.x); a1 += bfhi(v.x); a2 += bflo(v.y); a3 += bfhi(v.y);
        a4 += bflo(v.z); a5 += bfhi(v.z); a6 += bflo(v.w); a7 += bfhi(v.w);
    }
    float di = dinv[n];
    float o0 = fmaf(a0, di, bb0.x), o1 = fmaf(a1, di, bb0.y);
    float o2 = fmaf(a2, di, bb0.z), o3 = fmaf(a3, di, bb0.w);
    float o4 = fmaf(a4, di, bb1.x), o5 = fmaf(a5, di, bb1.y);
    float o6 = fmaf(a6, di, bb1.z), o7 = fmaf(a7, di, bb1.w);
    if (L1) {
        o0 = fmaxf(o0, 0.f); o1 = fmaxf(o1, 0.f); o2 = fmaxf(o2, 0.f); o3 = fmaxf(o3, 0.f);
        o4 = fmaxf(o4, 0.f); o5 = fmaxf(o5, 0.f); o6 = fmaxf(o6, 0.f); o7 = fmaxf(o7, 0.f);
        uint4 pk;
        pk.x = (uint)rne_bf16(o0) | ((uint)rne_bf16(o1) << 16);
        pk.y = (uint)rne_bf16(o2) | ((uint)rne_bf16(o3) << 16);
        pk.z = (uint)rne_bf16(o4) | ((uint)rne_bf16(o5) << 16);
        pk.w = (uint)rne_bf16(o6) | ((uint)rne_bf16(o7) << 16);
        ((uint4*)outv)[((size_t)h * N + n) * 8 + l] = pk;   // bf16 half-major
    } else {
        float4* op = (float4*)((float*)outv + (size_t)n * DF + h * 64 + l * 8);
        op[0] = make_float4(o0, o1, o2, o3);
        op[1] = make_float4(o4, o5, o6, o7);
    }
}

extern "C" void kernel_launch(void* const* d_in, const int* in_sizes, int n_in,
                              void* d_out, int out_size, void* d_ws, size_t ws_size,
                              hipStream_t stream) {
    const float* x  = (const float*)d_in[0];
    const int*   ei = (const int*)d_in[1];
    const float* W1 = (const float*)d_in[2];
    const float* b1 = (const float*)d_in[3];
    const float* W2 = (const float*)d_in[4];
    const float* b2 = (const float*)d_in[5];

    const int N = in_sizes[0] / DF;     // 50000
    const int E = in_sizes[1] / 2;      // 800000
    const int* src = ei;
    const int* dstp = ei + E;
    const int NB = (N + 255) >> 8;      // 196 coarse buckets
    const int SB = (E + 8191) / 8192;   // 98 scatter blocks

    float* out = (float*)d_out;
    char* ws = (char*)d_ws;
    size_t off = 0;
    auto carve = [&](size_t bytes) { void* p = ws + off; off += (bytes + 255) & ~(size_t)255; return p; };
    ushort* Hh     = (ushort*)carve((size_t)N * DF * sizeof(ushort));     // 12.8 MB, half-major
    ushort* Z1     = (ushort*)carve((size_t)N * DF * sizeof(ushort));     // 12.8 MB, half-major
    float*  dinv   = (float*)carve((size_t)N * sizeof(float));
    int*    rstart = (int*)carve((size_t)N * sizeof(int));
    int*    rend   = (int*)carve((size_t)N * sizeof(int));
    uint*   ebuf   = (uint*)carve((size_t)NB * CAP * sizeof(uint));       // 6.4 MB
    ushort* srcs   = (ushort*)carve((size_t)NB * CAP * sizeof(ushort));   // 3.2 MB
    int*    ccur   = (int*)carve(NBKT_MAX * sizeof(int));
    uint4*  Whi    = (uint4*)carve(2 * 2048 * sizeof(uint4));             // 64 KB
    uint4*  Wlo    = (uint4*)carve(2 * 2048 * sizeof(uint4));             // 64 KB

    const int gemm_b = (N + 127) / 128;
    const int gath_b = ((N + 127) / 128) * 8;   // (128-dst chunk) x (4 slices x 2 halves)

    // ---- CSR (scan-free) + dinv + W split ----
    hipMemsetAsync(ccur, 0, NBKT_MAX * sizeof(int), stream);
    scatter_wprep<<<SB + 16, 256, 0, stream>>>(src, dstp, ccur, ebuf, E, NB, SB, W1, W2, Whi, Wlo);
    bucket_sort<<<NB, 256, 0, stream>>>(ebuf, ccur, rstart, rend, dinv, srcs, N);

    // ---- layer 1: Hh = bf16((x@W1)*dinv); Z1 = bf16(relu(gather(Hh)+b1)) ----
    gemm_f32A<<<gemm_b, 256, 0, stream>>>(x, Whi, Wlo, dinv, Hh, N);
    half_gather<true><<<gath_b, 256, 0, stream>>>((const uint4*)Hh, dinv, rstart, rend, srcs, b1, Z1, N);

    // ---- layer 2: Hh = bf16((Z1@W2)*dinv); out = gather(Hh)+b2 ----
    gemm_bf16A<<<gemm_b, 256, 0, stream>>>(Z1, Whi + 2048, Wlo + 2048, dinv, Hh, N);
    half_gather<false><<<gath_b, 256, 0, stream>>>((const uint4*)Hh, dinv, rstart, rend, srcs, b2, out, N);
}